// Round 7
// baseline (441.388 us; speedup 1.0000x reference)
//
#include <hip/hip_runtime.h>

// MVURE layer: 3x GATConv + view attention fusion.
// Workspace layout (~137 MB):
//   feat   bf16 [3][N][128]   @ 0          (38,400,000 B)
//   el     f32  [3][N][8]     @ 38,400,000 ( 4,800,000 B)
//   er     f32  [3][N][8]     @ 43,200,000 ( 4,800,000 B)
//   views  f32  [3][N][128]   @ 48,000,000 (76,800,000 B)
//     overlay (consumed before gat_kernel writes views):
//       gbin  u32 [3][64][20480] @ ws+49,000,000 (15,728,640 B)
//   offs   i32  [3][N+1]      @ 124,800,000 (600,016 B padded)
//   esrc   i32  [3][E]        @ 126,000,016 (10,200,000 B)
//   gtail  i32  [3][64]       @ 136,800,016 (768 B)
//   scal   f32  logits[3],d[3],gc[6] @ 136,800,784 (48 B)

#define N_NODES 50000
#define DIM 128
#define OUTD 128
#define NH 8
#define NF 16
#define NE 850000            // 800000 random + 50000 self loops
#define NOFF 50001
#define NBUCK 49             // dst>>10 buckets (1024-node windows)
#define BCAP 20480           // per-bucket capacity (mean 17347, huge margin)
#define BIN_EPT 8
#define BIN_EPB 2048         // 256 threads * 8 edges

typedef float f32x4 __attribute__((ext_vector_type(4)));
typedef float f32x2 __attribute__((ext_vector_type(2)));
typedef __bf16 bf16x8 __attribute__((ext_vector_type(8)));
typedef unsigned short u16x8 __attribute__((ext_vector_type(8)));

static __device__ __forceinline__ float bf2f_lo(unsigned int u) {
  return __uint_as_float(u << 16);
}
static __device__ __forceinline__ float bf2f_hi(unsigned int u) {
  return __uint_as_float(u & 0xffff0000u);
}
static __device__ __forceinline__ f32x2 up2(unsigned int u) {
  f32x2 r;
  r.x = __uint_as_float(u << 16);
  r.y = __uint_as_float(u & 0xffff0000u);
  return r;
}
static __device__ __forceinline__ unsigned short f2bf(float f) {
  unsigned int u = __float_as_uint(f);
  unsigned int r = (u + 0x7fffu + ((u >> 16) & 1u)) >> 16;
  return (unsigned short)r;
}

// -------- GEMM: feat_v = x @ W_v^T (bf16 MFMA) + fused el/er ---------------
// Epilogue routes acc through LDS (wb reuse) for coalesced 16B feat stores,
// and computes el/er = feat . al/ar from the same LDS tile (elr fused).
__global__ __launch_bounds__(256) void gemm_feat_kernel(
    const float* __restrict__ x, const float* __restrict__ Ws,
    const float* __restrict__ Wt, const float* __restrict__ Wp,
    const float* __restrict__ al_s, const float* __restrict__ ar_s,
    const float* __restrict__ al_t, const float* __restrict__ ar_t,
    const float* __restrict__ al_p, const float* __restrict__ ar_p,
    unsigned short* __restrict__ feat, float* __restrict__ el,
    float* __restrict__ er) {
  __shared__ unsigned short xa[128 * 128];  // [row][k] bf16, XOR-swizzled
  __shared__ unsigned short wb[128 * 128];  // [o][k] bf16 -> C tile bf16
  __shared__ float alS[128], arS[128];
  const int t = threadIdx.x;
  const int n0 = blockIdx.x * 128;

  for (int i = 0; i < 16; ++i) {
    int flat = (i * 256 + t) * 4;
    int r = flat >> 7, c = flat & 127;
    float4 val = make_float4(0.f, 0.f, 0.f, 0.f);
    if (n0 + r < N_NODES) val = *(const float4*)(x + (size_t)(n0 + r) * DIM + c);
    int byteoff = (r * 256 + c * 2) ^ ((r & 7) << 4);
    unsigned short* p = (unsigned short*)((char*)xa + byteoff);
    p[0] = f2bf(val.x); p[1] = f2bf(val.y); p[2] = f2bf(val.z); p[3] = f2bf(val.w);
  }

  const int wave = t >> 6, lane = t & 63;
  const int wr = wave >> 1, wc = wave & 1;
  const int lrow = lane & 15;
  const int kgrp = lane >> 4;
  const int row = t >> 1, half = t & 1;  // epilogue mapping
  const int grow = n0 + row;

  for (int v = 0; v < 3; ++v) {
    const float* W = (v == 0) ? Ws : ((v == 1) ? Wt : Wp);
    const float* alv = (v == 0) ? al_s : ((v == 1) ? al_t : al_p);
    const float* arv = (v == 0) ? ar_s : ((v == 1) ? ar_t : ar_p);
    __syncthreads();
    for (int i = 0; i < 16; ++i) {
      int flat = (i * 256 + t) * 4;
      int r = flat >> 7, c = flat & 127;
      float4 val = *(const float4*)(W + r * DIM + c);
      int byteoff = (r * 256 + c * 2) ^ ((r & 7) << 4);
      unsigned short* p = (unsigned short*)((char*)wb + byteoff);
      p[0] = f2bf(val.x); p[1] = f2bf(val.y); p[2] = f2bf(val.z); p[3] = f2bf(val.w);
    }
    if (t < 128) alS[t] = alv[t];
    else arS[t - 128] = arv[t - 128];
    __syncthreads();

    f32x4 acc[4][4];
    for (int m = 0; m < 4; ++m)
      for (int n = 0; n < 4; ++n) acc[m][n] = (f32x4)0.f;

    for (int ks = 0; ks < 4; ++ks) {
      bf16x8 af[4], bfr[4];
      int kb2 = (ks * 32 + kgrp * 8) * 2;
      for (int m = 0; m < 4; ++m) {
        int r = wr * 64 + m * 16 + lrow;
        af[m] = *(const bf16x8*)((const char*)xa + ((r * 256 + kb2) ^ ((r & 7) << 4)));
      }
      for (int n = 0; n < 4; ++n) {
        int r = wc * 64 + n * 16 + lrow;
        bfr[n] = *(const bf16x8*)((const char*)wb + ((r * 256 + kb2) ^ ((r & 7) << 4)));
      }
      for (int m = 0; m < 4; ++m)
        for (int n = 0; n < 4; ++n)
          acc[m][n] = __builtin_amdgcn_mfma_f32_16x16x32_bf16(af[m], bfr[n], acc[m][n], 0, 0, 0);
    }

    __syncthreads();  // all MFMA reads of wb complete
    // write C tile (bf16) into wb, swizzled
    for (int m = 0; m < 4; ++m)
      for (int n = 0; n < 4; ++n) {
        int col = wc * 64 + n * 16 + lrow;
#pragma unroll
        for (int r4 = 0; r4 < 4; ++r4) {
          int r = wr * 64 + m * 16 + kgrp * 4 + r4;
          int bo = (r * 256 + col * 2) ^ ((r & 7) << 4);
          *(unsigned short*)((char*)wb + bo) = f2bf(acc[m][n][r4]);
        }
      }
    __syncthreads();

    // coalesced feat store: 2 threads per row, 128B each
    unsigned short* fv = feat + (size_t)v * N_NODES * OUTD;
    if (grow < N_NODES) {
      const int cb = half * 64;
#pragma unroll
      for (int i = 0; i < 8; ++i) {
        int c = cb + i * 8;
        u16x8 val = *(const u16x8*)((const char*)wb + ((row * 256 + c * 2) ^ ((row & 7) << 4)));
        *(u16x8*)(fv + (size_t)grow * OUTD + c) = val;
      }
      // fused el/er: heads half*4 .. half*4+3 of this row
      float4 elq, erq;
      float* elp = (float*)&elq;
      float* erp = (float*)&erq;
#pragma unroll
      for (int k = 0; k < 4; ++k) {
        int h = half * 4 + k;
        int c = h * 16;
        u16x8 f0 = *(const u16x8*)((const char*)wb + ((row * 256 + c * 2) ^ ((row & 7) << 4)));
        u16x8 f1 = *(const u16x8*)((const char*)wb + ((row * 256 + (c + 8) * 2) ^ ((row & 7) << 4)));
        float accl = 0.f, accr = 0.f;
#pragma unroll
        for (int f = 0; f < 8; ++f) {
          float v0 = bf2f_lo((unsigned int)(unsigned short)f0[f]);
          float v1 = bf2f_lo((unsigned int)(unsigned short)f1[f]);
          accl += v0 * alS[c + f] + v1 * alS[c + 8 + f];
          accr += v0 * arS[c + f] + v1 * arS[c + 8 + f];
        }
        elp[k] = accl; erp[k] = accr;
      }
      size_t eo = ((size_t)v * N_NODES + n0) * NH + t * 4;
      *(float4*)(el + eo) = elq;
      *(float4*)(er + eo) = erq;
    }
  }
}

// ---------------- CSR build: bucket-binned LDS counting sort ----------------
__global__ __launch_bounds__(256) void bin_kernel(
    const int* __restrict__ src_s, const int* __restrict__ dst_s,
    const int* __restrict__ src_t, const int* __restrict__ dst_t,
    const int* __restrict__ src_p, const int* __restrict__ dst_p,
    int* __restrict__ gtail, unsigned int* __restrict__ gbin) {
  const int v = blockIdx.y;
  const int* S = (v == 0) ? src_s : ((v == 1) ? src_t : src_p);
  const int* D = (v == 0) ? dst_s : ((v == 1) ? dst_t : dst_p);
  __shared__ int lhist[4][64], lbase[4][64];
  const int t = threadIdx.x;
  const int wave = t >> 6;
  ((int*)lhist)[t] = 0;
  __syncthreads();
  const int e0 = blockIdx.x * BIN_EPB + t * BIN_EPT;
  unsigned int pk[BIN_EPT];
  int bk[BIN_EPT], rk[BIN_EPT];
#pragma unroll
  for (int i = 0; i < BIN_EPT; ++i) {
    int e = e0 + i;
    if (e < NE) {
      unsigned int s = (unsigned int)S[e], d = (unsigned int)D[e];
      pk[i] = (s << 16) | d;
      bk[i] = (int)(d >> 10);
      rk[i] = atomicAdd(&lhist[wave][bk[i]], 1);
    } else {
      bk[i] = -1;
    }
  }
  __syncthreads();
  if (t < 64) {
    int c0 = lhist[0][t], c1 = lhist[1][t], c2 = lhist[2][t], c3 = lhist[3][t];
    int tot = c0 + c1 + c2 + c3;
    int gb = (tot > 0) ? atomicAdd(&gtail[v * 64 + t], tot) : 0;
    lbase[0][t] = gb;
    lbase[1][t] = gb + c0;
    lbase[2][t] = gb + c0 + c1;
    lbase[3][t] = gb + c0 + c1 + c2;
  }
  __syncthreads();
#pragma unroll
  for (int i = 0; i < BIN_EPT; ++i) {
    if (bk[i] >= 0) {
      int pos = lbase[wave][bk[i]] + rk[i];
      if (pos < BCAP)
        gbin[((size_t)v * 64 + bk[i]) * BCAP + pos] = pk[i];
    }
  }
}

__global__ __launch_bounds__(1024) void bucket_sort_kernel(
    const int* __restrict__ gtail, const unsigned int* __restrict__ gbin,
    int* __restrict__ offs, int* __restrict__ esrc) {
  __shared__ int lcur[1024];
  __shared__ int wsum[16];
  __shared__ int sh_bbase;
  __shared__ unsigned int sorted[BCAP];
  __shared__ int lhist[1024];
  const int v = blockIdx.y;
  const int b = blockIdx.x;
  const int t = threadIdx.x;
  const int wave = t >> 6, lane = t & 63;

  int cnt = gtail[v * 64 + b];
  if (cnt > BCAP) cnt = BCAP;
  const unsigned int* eb = gbin + ((size_t)v * 64 + b) * BCAP;

  if (t < 64) {
    int valb = (t < b) ? gtail[v * 64 + t] : 0;
#pragma unroll
    for (int m = 1; m < 64; m <<= 1) valb += __shfl_xor(valb, m, 64);
    if (t == 0) sh_bbase = valb;
  }
  lhist[t] = 0;
  __syncthreads();

  for (int e = t; e < cnt; e += 1024)
    atomicAdd(&lhist[eb[e] & 1023u], 1);
  __syncthreads();

  int val = lhist[t];
  int incl = val;
#pragma unroll
  for (int st = 1; st < 64; st <<= 1) {
    int o = __shfl_up(incl, st, 64);
    if (lane >= st) incl += o;
  }
  if (lane == 63) wsum[wave] = incl;
  __syncthreads();
  if (t < 64) {
    int wv = (lane < 16) ? wsum[lane] : 0;
    int winc = wv;
#pragma unroll
    for (int st = 1; st < 16; st <<= 1) {
      int o = __shfl_up(winc, st, 64);
      if (lane >= st) winc += o;
    }
    if (lane < 16) wsum[lane] = winc - wv;
  }
  __syncthreads();
  const int base = wsum[wave] + incl - val;
  lcur[t] = base;

  const int bbase = sh_bbase;
  if (b == 0 && t == 0) offs[v * NOFF] = 0;
  {
    int n = b * 1024 + t;
    if (n < N_NODES) offs[v * NOFF + n + 1] = bbase + base + val;
  }
  __syncthreads();

  for (int e = t; e < cnt; e += 1024) {
    unsigned int pk = eb[e];
    int pos = atomicAdd(&lcur[pk & 1023u], 1);
    sorted[pos] = pk >> 16;
  }
  __syncthreads();

  int* ev = esrc + (size_t)v * NE + bbase;
  for (int e = t; e < cnt; e += 1024) ev[e] = (int)sorted[e];
}

// ---------------- GAT aggregation: one wave per (view, dst node) ------------
// Lane layout: 8 edge-slots (g) x 8 heads (q). Each lane owns one (edge,head):
// one exp per lane (zero redundancy), 16 feats (32B) per lane, coalesced.
__global__ __launch_bounds__(256) void gat_kernel(
    const int* __restrict__ offs, const int* __restrict__ esrc,
    const float* __restrict__ el, const float* __restrict__ er,
    const unsigned short* __restrict__ feat,
    const float* __restrict__ b_s, const float* __restrict__ b_t,
    const float* __restrict__ b_p, float* __restrict__ views) {
  const int v = blockIdx.y;
  const int n = blockIdx.x * 4 + (threadIdx.x >> 6);
  const int lane = threadIdx.x & 63;
  const int g = lane >> 3;       // edge sub-slot 0..7
  const int q = lane & 7;        // head; features q*16 .. q*16+15
  const int* off_v = offs + v * NOFF;
  const int off0 = off_v[n];
  const int deg = off_v[n + 1] - off0;   // >= 1 (self loop)
  const int* es = esrc + (size_t)v * NE + off0;
  const float* el_v = el + (size_t)v * N_NODES * NH;
  const float er_q = er[((size_t)v * N_NODES + n) * NH + q];
  const unsigned short* featv = feat + (size_t)v * N_NODES * OUTD;

  f32x2 acc[8];
#pragma unroll
  for (int j = 0; j < 8; ++j) acc[j] = (f32x2)0.f;
  float sm = 0.f;

  // prologue: chunk 0
  int e = g;
  bool vld = e < deg;
  int s = es[vld ? e : 0];
  float l = el_v[s * NH + q];
  const unsigned short* fp = featv + (size_t)s * OUTD + q * 16;
  uint4 a0 = *(const uint4*)(fp);
  uint4 a1 = *(const uint4*)(fp + 8);

  for (int base = 0; base < deg; base += 8) {
    bool cvld = vld;
    float cl = l;
    uint4 c0 = a0, c1 = a1;
    int nb = base + 8;
    if (nb < deg) {  // prefetch next chunk
      e = nb + g;
      vld = e < deg;
      s = es[vld ? e : 0];
      l = el_v[s * NH + q];
      fp = featv + (size_t)s * OUTD + q * 16;
      a0 = *(const uint4*)(fp);
      a1 = *(const uint4*)(fp + 8);
    }
    float val = cl + er_q;
    val = fmaxf(val, 0.2f * val);     // leaky_relu(0.2)
    float aw = cvld ? __expf(val) : 0.f;
    sm += aw;
    acc[0] += aw * up2(c0.x);
    acc[1] += aw * up2(c0.y);
    acc[2] += aw * up2(c0.z);
    acc[3] += aw * up2(c0.w);
    acc[4] += aw * up2(c1.x);
    acc[5] += aw * up2(c1.y);
    acc[6] += aw * up2(c1.z);
    acc[7] += aw * up2(c1.w);
  }

  // reduce over the 8 edge-slots (lane bits 3,4,5)
#pragma unroll
  for (int m = 8; m < 64; m <<= 1) {
    sm += __shfl_xor(sm, m, 64);
#pragma unroll
    for (int j = 0; j < 8; ++j) {
      acc[j].x += __shfl_xor(acc[j].x, m, 64);
      acc[j].y += __shfl_xor(acc[j].y, m, 64);
    }
  }

  if (g < 4) {  // 32 lanes store the 512B row: float4 j=g of head q
    const float inv = 1.0f / sm;
    const float* bv = (v == 0) ? b_s : ((v == 1) ? b_t : b_p);
    int f0 = q * 16 + g * 4;
    float x0 = acc[2 * g].x * inv + bv[f0 + 0];
    float x1 = acc[2 * g].y * inv + bv[f0 + 1];
    float x2 = acc[2 * g + 1].x * inv + bv[f0 + 2];
    float x3 = acc[2 * g + 1].y * inv + bv[f0 + 3];
    float4 r = make_float4(fmaxf(x0, 0.f), fmaxf(x1, 0.f), fmaxf(x2, 0.f),
                           fmaxf(x3, 0.f));
    *(float4*)(views + ((size_t)v * N_NODES + n) * OUTD + f0) = r;
  }
}

// ---- fused view-reduction: logits[v] = sum_n (V Wq^T + bq).(V Wk^T + bk),
//      dsum[v] = sum(V .* Wm). All 3 views per block -> Wm tile fetched once.
__global__ __launch_bounds__(256) void viewred_kernel(
    const float* __restrict__ views, const float* __restrict__ Wq,
    const float* __restrict__ bq, const float* __restrict__ Wk,
    const float* __restrict__ bk, const float* __restrict__ Wm,
    float* __restrict__ logits, float* __restrict__ dsum) {
  __shared__ unsigned short vt[128 * 128];  // V tile bf16, XOR-swizzled
  __shared__ unsigned short wq[16 * 128];   // Wq bf16, XOR-swizzled
  __shared__ unsigned short wk[16 * 128];
  __shared__ float redq[4], redd[4];
  const int n0 = blockIdx.x * 128;
  const int t = threadIdx.x;
  const int wave = t >> 6, lane = t & 63;
  const int lrow = lane & 15;
  const int kgrp = lane >> 4;

  {
    int flat = t * 8;
    int r = flat >> 7, c = flat & 127;
    int byteoff = (r * 256 + c * 2) ^ ((r & 7) << 4);
    float4 qa = *(const float4*)(Wq + flat);
    float4 qb = *(const float4*)(Wq + flat + 4);
    u16x8 oq;
    oq[0] = f2bf(qa.x); oq[1] = f2bf(qa.y); oq[2] = f2bf(qa.z); oq[3] = f2bf(qa.w);
    oq[4] = f2bf(qb.x); oq[5] = f2bf(qb.y); oq[6] = f2bf(qb.z); oq[7] = f2bf(qb.w);
    *(u16x8*)((char*)wq + byteoff) = oq;
    float4 ka = *(const float4*)(Wk + flat);
    float4 kb = *(const float4*)(Wk + flat + 4);
    u16x8 ok;
    ok[0] = f2bf(ka.x); ok[1] = f2bf(ka.y); ok[2] = f2bf(ka.z); ok[3] = f2bf(ka.w);
    ok[4] = f2bf(kb.x); ok[5] = f2bf(kb.y); ok[6] = f2bf(kb.z); ok[7] = f2bf(kb.w);
    *(u16x8*)((char*)wk + byteoff) = ok;
  }

  const float bqv = bq[lrow];
  const float bkv = bk[lrow];

  for (int v = 0; v < 3; ++v) {
    const float* Vv = views + (size_t)v * N_NODES * OUTD;
    float dp = 0.f;
    for (int i = 0; i < 8; ++i) {
      int flat = (i * 256 + t) * 8;
      int r = flat >> 7, c = flat & 127;
      int row = n0 + r;
      u16x8 o = (u16x8)0;
      if (row < N_NODES) {
        size_t goff = (size_t)row * OUTD + c;
        float4 a = *(const float4*)(Vv + goff);
        float4 b = *(const float4*)(Vv + goff + 4);
        float4 wa = *(const float4*)(Wm + goff);
        float4 wb2 = *(const float4*)(Wm + goff + 4);
        dp += a.x * wa.x + a.y * wa.y + a.z * wa.z + a.w * wa.w;
        dp += b.x * wb2.x + b.y * wb2.y + b.z * wb2.z + b.w * wb2.w;
        o[0] = f2bf(a.x); o[1] = f2bf(a.y); o[2] = f2bf(a.z); o[3] = f2bf(a.w);
        o[4] = f2bf(b.x); o[5] = f2bf(b.y); o[6] = f2bf(b.z); o[7] = f2bf(b.w);
      }
      int byteoff = (r * 256 + c * 2) ^ ((r & 7) << 4);
      *(u16x8*)((char*)vt + byteoff) = o;
    }
    __syncthreads();

    float qk = 0.f;
    f32x4 accQ[2], accK[2];
    accQ[0] = (f32x4)0.f; accQ[1] = (f32x4)0.f;
    accK[0] = (f32x4)0.f; accK[1] = (f32x4)0.f;
    for (int ks = 0; ks < 4; ++ks) {
      int kb2 = (ks * 32 + kgrp * 8) * 2;
      int rb = lrow;
      bf16x8 bqf = *(const bf16x8*)((const char*)wq + ((rb * 256 + kb2) ^ ((rb & 7) << 4)));
      bf16x8 bkf = *(const bf16x8*)((const char*)wk + ((rb * 256 + kb2) ^ ((rb & 7) << 4)));
#pragma unroll
      for (int m = 0; m < 2; ++m) {
        int r = (wave * 2 + m) * 16 + lrow;
        bf16x8 af = *(const bf16x8*)((const char*)vt + ((r * 256 + kb2) ^ ((r & 7) << 4)));
        accQ[m] = __builtin_amdgcn_mfma_f32_16x16x32_bf16(af, bqf, accQ[m], 0, 0, 0);
        accK[m] = __builtin_amdgcn_mfma_f32_16x16x32_bf16(af, bkf, accK[m], 0, 0, 0);
      }
    }
#pragma unroll
    for (int m = 0; m < 2; ++m) {
#pragma unroll
      for (int j = 0; j < 4; ++j) {
        int row = n0 + (wave * 2 + m) * 16 + kgrp * 4 + j;
        if (row < N_NODES) qk += (accQ[m][j] + bqv) * (accK[m][j] + bkv);
      }
    }

#pragma unroll
    for (int m = 1; m < 64; m <<= 1) {
      qk += __shfl_xor(qk, m, 64);
      dp += __shfl_xor(dp, m, 64);
    }
    if (lane == 0) { redq[wave] = qk; redd[wave] = dp; }
    __syncthreads();
    if (t == 0) {
      atomicAdd(&logits[v], redq[0] + redq[1] + redq[2] + redq[3]);
      atomicAdd(&dsum[v], redd[0] + redd[1] + redd[2] + redd[3]);
    }
    __syncthreads();  // vt reused next view
  }
}

// ---------------- scalar chain: softmax + sigmoid gates ---------------------
__global__ void scalar_kernel(const float* __restrict__ logits,
                              const float* __restrict__ dsum,
                              const float* __restrict__ bm, float* __restrict__ gc) {
  if (threadIdx.x == 0 && blockIdx.x == 0) {
    const float scale = 1.0f / sqrtf((float)(NF * N_NODES));
    float l0 = logits[0] * scale, l1 = logits[1] * scale, l2 = logits[2] * scale;
    float mx = fmaxf(l0, fmaxf(l1, l2));
    float e0 = __expf(l0 - mx), e1 = __expf(l1 - mx), e2 = __expf(l2 - mx);
    float inv = 1.0f / (e0 + e1 + e2);
    float g0 = 0.8f * e0 * inv + 0.2f;
    float g1 = 0.8f * e1 * inv + 0.2f;
    float g2 = 0.8f * e2 * inv + 0.2f;
    float bmv = bm[0];
    float o0 = 1.0f / (1.0f + __expf(-(g0 * dsum[0] + bmv)));
    float o1 = 1.0f / (1.0f + __expf(-(g1 * dsum[1] + bmv)));
    float o2 = 1.0f / (1.0f + __expf(-(g2 * dsum[2] + bmv)));
    gc[0] = g0; gc[1] = g1; gc[2] = g2;
    gc[3] = o0 * g0; gc[4] = o1 * g1; gc[5] = o2 * g2;
  }
}

// ---------------- epilogue: mv + result -------------------------------------
__global__ __launch_bounds__(256) void final_kernel(
    const float* __restrict__ views, const float* __restrict__ gc,
    float* __restrict__ out) {
  const size_t NT = (size_t)N_NODES * OUTD;
  size_t base = ((size_t)blockIdx.x * 256 + threadIdx.x) * 4;
  if (base >= NT) return;
  float g0 = gc[0], g1 = gc[1], g2 = gc[2], c0 = gc[3], c1 = gc[4], c2 = gc[5];
  float4 a0 = *(const float4*)(views + base);
  float4 a1 = *(const float4*)(views + NT + base);
  float4 a2 = *(const float4*)(views + 2 * NT + base);
  float4 mv;
  mv.x = c0 * a0.x + c1 * a1.x + c2 * a2.x;
  mv.y = c0 * a0.y + c1 * a1.y + c2 * a2.y;
  mv.z = c0 * a0.z + c1 * a1.z + c2 * a2.z;
  mv.w = c0 * a0.w + c1 * a1.w + c2 * a2.w;
  *(float4*)(out + base) = mv;
  float4 r;
  r.x = 0.5f * (g0 * a0.x) + 0.5f * mv.x;
  r.y = 0.5f * (g0 * a0.y) + 0.5f * mv.y;
  r.z = 0.5f * (g0 * a0.z) + 0.5f * mv.z;
  r.w = 0.5f * (g0 * a0.w) + 0.5f * mv.w;
  *(float4*)(out + NT + base) = r;
  r.x = 0.5f * (g1 * a1.x) + 0.5f * mv.x;
  r.y = 0.5f * (g1 * a1.y) + 0.5f * mv.y;
  r.z = 0.5f * (g1 * a1.z) + 0.5f * mv.z;
  r.w = 0.5f * (g1 * a1.w) + 0.5f * mv.w;
  *(float4*)(out + 2 * NT + base) = r;
  r.x = 0.5f * (g2 * a2.x) + 0.5f * mv.x;
  r.y = 0.5f * (g2 * a2.y) + 0.5f * mv.y;
  r.z = 0.5f * (g2 * a2.z) + 0.5f * mv.z;
  r.w = 0.5f * (g2 * a2.w) + 0.5f * mv.w;
  *(float4*)(out + 3 * NT + base) = r;
}

extern "C" void kernel_launch(void* const* d_in, const int* in_sizes, int n_in,
                              void* d_out, int out_size, void* d_ws, size_t ws_size,
                              hipStream_t stream) {
  const float* x = (const float*)d_in[0];
  const int* src_s = (const int*)d_in[1];
  const int* dst_s = (const int*)d_in[2];
  const int* src_t = (const int*)d_in[3];
  const int* dst_t = (const int*)d_in[4];
  const int* src_p = (const int*)d_in[5];
  const int* dst_p = (const int*)d_in[6];
  const float* W_s = (const float*)d_in[7];
  const float* al_s = (const float*)d_in[8];
  const float* ar_s = (const float*)d_in[9];
  const float* b_s = (const float*)d_in[10];
  const float* W_t = (const float*)d_in[11];
  const float* al_t = (const float*)d_in[12];
  const float* ar_t = (const float*)d_in[13];
  const float* b_t = (const float*)d_in[14];
  const float* W_p = (const float*)d_in[15];
  const float* al_p = (const float*)d_in[16];
  const float* ar_p = (const float*)d_in[17];
  const float* b_p = (const float*)d_in[18];
  const float* Wq = (const float*)d_in[19];
  const float* bq = (const float*)d_in[20];
  const float* Wk = (const float*)d_in[21];
  const float* bk = (const float*)d_in[22];
  const float* Wm = (const float*)d_in[23];
  const float* bm = (const float*)d_in[24];
  float* out = (float*)d_out;

  char* ws = (char*)d_ws;
  unsigned short* feat = (unsigned short*)ws;
  float* el = (float*)(ws + 38400000);
  float* er = (float*)(ws + 43200000);
  float* views = (float*)(ws + 48000000);
  int* offs = (int*)(ws + 124800000);
  int* esrc = (int*)(ws + 126000016);
  int* gtail = (int*)(ws + 136800016);     // 3*64 ints = 768 B
  float* scal = (float*)(ws + 136800784);  // logits[3], dsum[3], gc[6]

  // overlay inside the (not yet written) views buffer
  unsigned int* gbin = (unsigned int*)(ws + 49000000);  // 15,728,640 B

  hipMemsetAsync(gtail, 0, 768 + 48, stream);

  gemm_feat_kernel<<<dim3(391), dim3(256), 0, stream>>>(
      x, W_s, W_t, W_p, al_s, ar_s, al_t, ar_t, al_p, ar_p, feat, el, er);
  bin_kernel<<<dim3((NE + BIN_EPB - 1) / BIN_EPB, 3), dim3(256), 0, stream>>>(
      src_s, dst_s, src_t, dst_t, src_p, dst_p, gtail, gbin);
  bucket_sort_kernel<<<dim3(NBUCK, 3), dim3(1024), 0, stream>>>(
      gtail, gbin, offs, esrc);
  gat_kernel<<<dim3(12500, 3), dim3(256), 0, stream>>>(
      offs, esrc, el, er, feat, b_s, b_t, b_p, views);
  viewred_kernel<<<dim3(391), dim3(256), 0, stream>>>(
      views, Wq, bq, Wk, bk, Wm, scal, scal + 3);
  scalar_kernel<<<dim3(1), dim3(64), 0, stream>>>(scal, scal + 3, bm, scal + 6);
  final_kernel<<<dim3(6250), dim3(256), 0, stream>>>(views, scal + 6, out);
}